// Round 10
// baseline (799.316 us; speedup 1.0000x reference)
//
#include <hip/hip_runtime.h>
#include <hip/hip_bf16.h>

typedef short s16x8 __attribute__((ext_vector_type(8)));      // 8 bf16 (4 VGPRs)
typedef float f32x16 __attribute__((ext_vector_type(16)));
typedef unsigned short us8 __attribute__((ext_vector_type(8)));

#define HE    1024
#define SEQ   4096
#define NBAT  32
#define MTOT  (NBAT * SEQ)   // 131072
#define BM    256            // rows per block
#define BN    256            // cols per block (4 n-slices)
#define BK    32             // k per tile
#define NT    32             // K tiles
#define APITCH 72            // bf16 A row pitch: 64 B data + 8 pad (bank-spread)

__device__ __forceinline__ unsigned short f2bf(float f) {
    unsigned u = __builtin_bit_cast(unsigned, f);
    u += 0x7FFFu + ((u >> 16) & 1u);
    return (unsigned short)(u >> 16);
}

__device__ __forceinline__ float tanh_fast(float x) {
    float e = __expf(2.0f * x);
    return 1.0f - 2.0f / (e + 1.0f);
}

__device__ __forceinline__ void gload_lds16(const void* g, void* l) {
    __builtin_amdgcn_global_load_lds(
        (const __attribute__((address_space(1))) unsigned int*)g,
        (__attribute__((address_space(3))) unsigned int*)l,
        16, 0, 0);
}

// barrier WITHOUT implicit vmcnt drain (we drain explicitly where needed)
#define WG_SYNC() do {                                         \
    asm volatile("s_waitcnt lgkmcnt(0)" ::: "memory");         \
    __builtin_amdgcn_s_barrier();                              \
} while (0)

// ---- h_proj partials
__global__ void k_hproj(const float* __restrict__ hidden, const float* __restrict__ W,
                        float* __restrict__ cpart) {
    int b = blockIdx.x >> 3, kc = blockIdx.x & 7;
    int h = threadIdx.x;
    const float* hv = hidden + (NBAT + b) * HE;   // hidden[-1]
    int k0 = kc * 128;
    float acc = 0.f;
    for (int j = 0; j < 128; ++j)
        acc = fmaf(hv[k0 + j], W[(k0 + j) * HE + h], acc);
    cpart[(b * 8 + kc) * HE + h] = acc;
}

__global__ void k_cfinal(const float* __restrict__ cpart, const float* __restrict__ b_attn,
                         float* __restrict__ c) {
    int b = blockIdx.x, h = threadIdx.x;
    float s = b_attn[h];
    #pragma unroll
    for (int kc = 0; kc < 8; ++kc) s += cpart[(b * 8 + kc) * HE + h];
    c[b * HE + h] = s;
}

// ---- pack W_e (= W_attn[He:]) into 32x32x16 B-fragment order, tiled (nsl, kt):
// frag f = ks*8 + cf (1 KB): lane l holds bf16
//   W_e[kt*32 + ks*16 + (l>>5)*8 + i][nsl*256 + cf*32 + (l&31)]
__global__ void k_pack(const float* __restrict__ W, unsigned short* __restrict__ Wp) {
    int gid = blockIdx.x * blockDim.x + threadIdx.x;   // 131072 threads
    int l = gid & 63, frag = (gid >> 6) & 15, kt = (gid >> 10) & 31, nsl = gid >> 15;
    int ks = frag >> 3, cf = frag & 7;
    int krow = HE + kt * 32 + ks * 16 + ((l >> 5) * 8);
    int col  = nsl * 256 + cf * 32 + (l & 31);
    us8 v;
    #pragma unroll
    for (int i = 0; i < 8; ++i) v[i] = f2bf(W[(krow + i) * HE + col]);
    *(us8*)(Wp + (long)gid * 8) = v;
}

// ---- main GEMM: 256x256 tile, BK=32, 512 thr (8 waves 2Mx4N, wave 128x64,
//      32x32x16). A: reg-staged 1KB-contig fp32 loads, cvt_pk->bf16, ds_write
//      at tile end (T14). B: fragment-linear gload_lds (1KB contig). All VMEM
//      waits at tile boundary with >= 1-tile slack. No setprio.
__global__ __launch_bounds__(512, 2) void k_main(
    const float* __restrict__ E, const unsigned short* __restrict__ Wp,
    const float* __restrict__ C, const float* __restrict__ VW,
    float* __restrict__ spart)
{
    __shared__ __align__(16) char Ab[2][BM * APITCH];   // 2 x 18 KB bf16 A tile
    __shared__ __align__(16) char Bb[2][16384];         // 2 x 16 KB bf16 B frags
    __shared__ float smred[BM][4];

    const int tid  = threadIdx.x;
    const int lane = tid & 63;
    const int wv   = tid >> 6;           // 8 waves
    const int mh   = wv >> 2;            // m-half (128 rows)
    const int nq   = wv & 3;             // n-quarter (64 cols)
    const int l31  = lane & 31, lh = lane >> 5;

    // XCD-chunked swizzle: 4 n-slice siblings adjacent on one XCD
    const int wgid = blockIdx.x;
    const int idx  = (wgid & 7) * 256 + (wgid >> 3);   // bijective (2048 = 8*256)
    const int nsl  = idx & 3;
    const int m0   = (idx >> 2) * BM;
    const int bb   = m0 >> 12;

    // A staging: instr j reads row (m0 + j*64 + tid>>3), 16B unit (tid&7)
    const float* gA = E + (long)(m0 + (tid >> 3)) * HE + (tid & 7) * 4;
    // A LDS write: row j*64 + (tid>>3), byte (tid&7)*8 within 64B row data
    const int awr = (tid >> 3) * APITCH + (tid & 7) * 8;

    // A read rows: mh*128 + rf*32 + l31
    int arow[4];
    #pragma unroll
    for (int rf = 0; rf < 4; ++rf)
        arow[rf] = (mh * 128 + rf * 32 + l31) * APITCH;

    // B source base (bytes): ((nsl*32 + kt)*16 + frag)*1024 + lane*16
    const char* WpBy = (const char*)Wp + (((long)nsl * 32) << 14);

    f32x16 acc[4][2];
    #pragma unroll
    for (int rf = 0; rf < 4; ++rf)
        #pragma unroll
        for (int cf = 0; cf < 2; ++cf)
            #pragma unroll
            for (int e = 0; e < 16; ++e) acc[rf][cf][e] = 0.f;

#define A_ISSUE01(t1) do {                                                       \
    fA0 = *(const float4*)(gA + ((long)0 * 64) * HE + (t1) * BK);                \
    fA1 = *(const float4*)(gA + ((long)1 * 64) * HE + (t1) * BK);                \
} while (0)

#define A_ISSUE23(t1) do {                                                       \
    fA2 = *(const float4*)(gA + ((long)2 * 64) * HE + (t1) * BK);                \
    fA3 = *(const float4*)(gA + ((long)3 * 64) * HE + (t1) * BK);                \
} while (0)

// cvt 4 fp32 -> 4 bf16 (8B) and ds_write_b64 at row j*64+(tid>>3)
#define A_WRITE1(pbuf, j, fv) do {                                               \
    int d0_, d1_;                                                                \
    asm("v_cvt_pk_bf16_f32 %0, %1, %2" : "=v"(d0_) : "v"((fv).x), "v"((fv).y));  \
    asm("v_cvt_pk_bf16_f32 %0, %1, %2" : "=v"(d1_) : "v"((fv).z), "v"((fv).w));  \
    int2 w_; w_.x = d0_; w_.y = d1_;                                             \
    *(int2*)(&Ab[pbuf][0] + (j) * 64 * APITCH + awr) = w_;                       \
} while (0)

#define B_ISSUE1(pbuf, t1, j)                                                    \
    gload_lds16(WpBy + ((((long)(t1) * 16) + wv * 2 + (j)) << 10) + (lane << 4), \
                &Bb[pbuf][0] + ((wv * 2 + (j)) << 10));

#define KS_COMPUTE(pbuf, ks) do {                                                \
    s16x8 a_[4], b_[2];                                                          \
    const int ao_ = ((ks) * 2 + lh) * 16;                                        \
    _Pragma("unroll")                                                            \
    for (int rf = 0; rf < 4; ++rf)                                               \
        a_[rf] = *(const s16x8*)(&Ab[pbuf][0] + arow[rf] + ao_);                 \
    _Pragma("unroll")                                                            \
    for (int cf = 0; cf < 2; ++cf)                                               \
        b_[cf] = *(const s16x8*)(&Bb[pbuf][0] +                                  \
                    (((ks) * 8 + nq * 2 + cf) << 10) + (lane << 4));             \
    _Pragma("unroll")                                                            \
    for (int rf = 0; rf < 4; ++rf)                                               \
        _Pragma("unroll")                                                        \
        for (int cf = 0; cf < 2; ++cf)                                           \
            acc[rf][cf] = __builtin_amdgcn_mfma_f32_32x32x16_bf16(               \
                a_[rf], b_[cf], acc[rf][cf], 0, 0, 0);                           \
} while (0)

    float4 fA0, fA1, fA2, fA3;

    // prologue: stage tile 0 completely
    A_ISSUE01(0); A_ISSUE23(0);
    B_ISSUE1(0, 0, 0); B_ISSUE1(0, 0, 1);
    A_WRITE1(0, 0, fA0); A_WRITE1(0, 1, fA1);
    A_WRITE1(0, 2, fA2); A_WRITE1(0, 3, fA3);
    asm volatile("s_waitcnt vmcnt(0)" ::: "memory");
    __builtin_amdgcn_s_barrier();

    for (int t = 0; t < NT; ++t) {
        const int pb = t & 1;
        const bool more = (t + 1 < NT);

        // phase ks=0: issue half of t+1 staging, then 8 MFMA
        if (more) { A_ISSUE01(t + 1); B_ISSUE1(pb ^ 1, t + 1, 0); }
        KS_COMPUTE(pb, 0);

        // phase ks=1: issue second half, then 8 MFMA
        if (more) { A_ISSUE23(t + 1); B_ISSUE1(pb ^ 1, t + 1, 1); }
        KS_COMPUTE(pb, 1);

        // tile tail: cvt+write A(t+1) (compiler waits the fA loads, issued a
        // full tile ago); drain B(t+1) gloads; lgkm barrier
        if (more) {
            A_WRITE1(pb ^ 1, 0, fA0); A_WRITE1(pb ^ 1, 1, fA1);
            A_WRITE1(pb ^ 1, 2, fA2); A_WRITE1(pb ^ 1, 3, fA3);
        }
        asm volatile("s_waitcnt vmcnt(0)" ::: "memory");
        WG_SYNC();
    }

#undef A_ISSUE01
#undef A_ISSUE23
#undef A_WRITE1
#undef B_ISSUE1
#undef KS_COMPUTE

    // fused epilogue: partial score over this block's 256 cols
    float cv[2], vv[2];
    #pragma unroll
    for (int cf = 0; cf < 2; ++cf) {
        int col = nsl * 256 + nq * 64 + cf * 32 + l31;
        cv[cf] = C[bb * HE + col];
        vv[cf] = VW[col];
    }
    #pragma unroll
    for (int rf = 0; rf < 4; ++rf) {
        #pragma unroll
        for (int reg = 0; reg < 16; ++reg) {
            float pS = 0.f;
            #pragma unroll
            for (int cf = 0; cf < 2; ++cf)
                pS += tanh_fast(acc[rf][cf][reg] + cv[cf]) * vv[cf];
            pS += __shfl_xor(pS, 1);
            pS += __shfl_xor(pS, 2);
            pS += __shfl_xor(pS, 4);
            pS += __shfl_xor(pS, 8);
            pS += __shfl_xor(pS, 16);
            if (l31 == 0) {
                int row = mh * 128 + rf * 32 + (reg & 3) + 8 * (reg >> 2) + 4 * lh;
                smred[row][nq] = pS;
            }
        }
    }
    __syncthreads();
    if (tid < BM) {
        float s = smred[tid][0] + smred[tid][1] + smred[tid][2] + smred[tid][3];
        spart[(long)nsl * MTOT + m0 + tid] = s;
    }
}

// ---- softmax over S=4096 per batch row (sums 4 col-slice partials)
__global__ void k_softmax(const float* __restrict__ spart, float* __restrict__ out) {
    __shared__ float red[16];
    __shared__ float red2[16];
    int b = blockIdx.x, tid = threadIdx.x;
    float v[4];
    float mx = -1e30f;
    #pragma unroll
    for (int j = 0; j < 4; ++j) {
        long i = (long)b * SEQ + tid + j * 1024;
        v[j] = spart[i] + spart[MTOT + i] + spart[2L * MTOT + i] + spart[3L * MTOT + i];
        mx = fmaxf(mx, v[j]);
    }
    #pragma unroll
    for (int off = 32; off; off >>= 1) mx = fmaxf(mx, __shfl_xor(mx, off));
    if ((tid & 63) == 0) red[tid >> 6] = mx;
    __syncthreads();
    mx = red[0];
    #pragma unroll
    for (int i = 1; i < 16; ++i) mx = fmaxf(mx, red[i]);
    float sum = 0.f;
    #pragma unroll
    for (int j = 0; j < 4; ++j) { v[j] = expf(v[j] - mx); sum += v[j]; }
    #pragma unroll
    for (int off = 32; off; off >>= 1) sum += __shfl_xor(sum, off);
    if ((tid & 63) == 0) red2[tid >> 6] = sum;
    __syncthreads();
    sum = 0.f;
    #pragma unroll
    for (int i = 0; i < 16; ++i) sum += red2[i];
    float inv = 1.0f / sum;
    #pragma unroll
    for (int j = 0; j < 4; ++j) out[b * SEQ + tid + j * 1024] = v[j] * inv;
}

extern "C" void kernel_launch(void* const* d_in, const int* in_sizes, int n_in,
                              void* d_out, int out_size, void* d_ws, size_t ws_size,
                              hipStream_t stream)
{
    const float* hidden = (const float*)d_in[0];
    const float* enc    = (const float*)d_in[1];
    const float* W      = (const float*)d_in[2];
    const float* b_attn = (const float*)d_in[3];
    const float* v_w    = (const float*)d_in[4];
    float* out          = (float*)d_out;

    char* ws = (char*)d_ws;
    unsigned short* Wp = (unsigned short*)(ws);                        // 2 MB packed bf16 W_e
    float* cpart       = (float*)(ws + (2u << 20));                    // 1 MB
    float* Cc          = (float*)(ws + (3u << 20));                    // 128 KB
    float* spart       = (float*)(ws + (3u << 20) + (128u << 10));     // 4 x 512 KB partials

    k_pack   <<<512, 256,  0, stream>>>(W, Wp);
    k_hproj  <<<256, 1024, 0, stream>>>(hidden, W, cpart);
    k_cfinal <<<32,  1024, 0, stream>>>(cpart, b_attn, Cc);
    k_main   <<<2048, 512, 0, stream>>>(enc, Wp, Cc, v_w, spart);
    k_softmax<<<32,  1024, 0, stream>>>(spart, out);
}

// Round 11
// 409.451 us; speedup vs baseline: 1.9522x; 1.9522x over previous
//
#include <hip/hip_runtime.h>
#include <hip/hip_bf16.h>

typedef short s16x8 __attribute__((ext_vector_type(8)));      // 8 bf16 (4 VGPRs)
typedef float f32x4 __attribute__((ext_vector_type(4)));
typedef unsigned short us8 __attribute__((ext_vector_type(8)));

#define HE   1024
#define SEQ  4096
#define NBAT 32
#define MTOT (NBAT * SEQ)    // 131072
#define BM   256             // rows per block
#define BK   64              // k per tile
#define NT   16              // K tiles

__device__ __forceinline__ unsigned short f2bf(float f) {
    unsigned u = __builtin_bit_cast(unsigned, f);
    u += 0x7FFFu + ((u >> 16) & 1u);
    return (unsigned short)(u >> 16);
}

__device__ __forceinline__ float tanh_fast(float x) {
    float e = __expf(2.0f * x);
    return 1.0f - 2.0f / (e + 1.0f);
}

__device__ __forceinline__ void gload_lds16(const void* g, void* l) {
    __builtin_amdgcn_global_load_lds(
        (const __attribute__((address_space(1))) unsigned int*)g,
        (__attribute__((address_space(3))) unsigned int*)l,
        16, 0, 0);
}

// ---- h_proj partials
__global__ void k_hproj(const float* __restrict__ hidden, const float* __restrict__ W,
                        float* __restrict__ cpart) {
    int b = blockIdx.x >> 3, kc = blockIdx.x & 7;
    int h = threadIdx.x;
    const float* hv = hidden + (NBAT + b) * HE;   // hidden[-1]
    int k0 = kc * 128;
    float acc = 0.f;
    for (int j = 0; j < 128; ++j)
        acc = fmaf(hv[k0 + j], W[(k0 + j) * HE + h], acc);
    cpart[(b * 8 + kc) * HE + h] = acc;
}

__global__ void k_cfinal(const float* __restrict__ cpart, const float* __restrict__ b_attn,
                         float* __restrict__ c) {
    int b = blockIdx.x, h = threadIdx.x;
    float s = b_attn[h];
    #pragma unroll
    for (int kc = 0; kc < 8; ++kc) s += cpart[(b * 8 + kc) * HE + h];
    c[b * HE + h] = s;
}

// ---- pack W_e (= W_attn[He:]) into 16x16x32 MFMA B-fragment order (r8-proven):
// frag = ks*16+fn (1 KB): lane l holds bf16
//   W_e[kt*64 + ks*32 + (l>>4)*8 + i][nsl*256 + fn*16 + (l&15)]
__global__ void k_pack(const float* __restrict__ W, unsigned short* __restrict__ Wp) {
    int gid = blockIdx.x * blockDim.x + threadIdx.x;   // 131072 threads
    int l = gid & 63, frag = (gid >> 6) & 31, kt = (gid >> 11) & 15, nsl = gid >> 15;
    int ks = frag >> 4, fn = frag & 15;
    int krow = HE + kt * 64 + ks * 32 + ((l >> 4) * 8);
    int col  = nsl * 256 + fn * 16 + (l & 15);
    us8 v;
    #pragma unroll
    for (int i = 0; i < 8; ++i) v[i] = f2bf(W[(krow + i) * HE + col]);
    *(us8*)(Wp + (long)gid * 8) = v;
}

// ---- main GEMM: 256x256 tile, BK=64, 512 thr (8 waves 2Mx4N, wave 128x64).
//      A: reg-staged row-quad 256B-slab loads, cvt_pk->bf16, ds_write at FULL-
//      tile distance; B: fragment-linear gload_lds issued AFTER A-floats so the
//      dataflow wait leaves B in flight. 4 phases/tile, per-phase barrier,
//      vmcnt(0) only at tile end (>=1.5 phases of slack).
__global__ __launch_bounds__(512, 2) void k_main(
    const float* __restrict__ E, const unsigned short* __restrict__ Wp,
    const float* __restrict__ C, const float* __restrict__ VW,
    float* __restrict__ spart)
{
    __shared__ __align__(16) char Ab[2][32768];   // 256 rows x 128 B bf16, XOR-swz
    __shared__ __align__(16) char Bb[2][32768];   // 32 frags x 1 KB, linear
    __shared__ float smred[BM][4];

    const int tid  = threadIdx.x;
    const int lane = tid & 63;
    const int wv   = tid >> 6;
    const int mh   = wv >> 2;            // m-half (128 rows)
    const int nq   = wv & 3;             // n-quarter (64 cols)
    const int l15  = lane & 15;
    const int lh   = lane >> 4;

    // XCD-chunked swizzle: 4 n-slice siblings of a stripe adjacent on one XCD
    const int wgid = blockIdx.x;
    const int idx  = (wgid & 7) * 256 + (wgid >> 3);   // bijective (2048 = 8*256)
    const int nsl  = idx & 3;
    const int m0   = (idx >> 2) * BM;
    const int bb   = m0 >> 12;

    // A staging: instr j covers rows m0+wv*32+j*4+lh, 16 B at k-pos l15*4 (fp32)
    const float* gA = E + (long)(m0 + wv * 32 + lh) * HE + l15 * 4;
    const char* WpB = (const char*)Wp + ((long)nsl << 19);

    // A read: row = mh*128 + (rfi>>2)*64 + (rfi&3)*16 + l15; unit = (s*4+lh)^(row&7)
    const int axr = l15 & 7;
    int abase[8];
    #pragma unroll
    for (int rfi = 0; rfi < 8; ++rfi)
        abase[rfi] = (mh * 128 + (rfi >> 2) * 64 + (rfi & 3) * 16 + l15) * 128;

    f32x4 acc[8][4];
    #pragma unroll
    for (int rfi = 0; rfi < 8; ++rfi)
        #pragma unroll
        for (int cfi = 0; cfi < 4; ++cfi)
            { acc[rfi][cfi][0]=0.f; acc[rfi][cfi][1]=0.f; acc[rfi][cfi][2]=0.f; acc[rfi][cfi][3]=0.f; }

    float4 fS[8];

#define A_ISSUE_H1(t1) { _Pragma("unroll") for (int j = 0; j < 4; ++j)           \
    fS[j] = *(const float4*)(gA + j * 4 * HE + (t1) * BK); }

#define A_ISSUE_H2(t1) { _Pragma("unroll") for (int j = 4; j < 8; ++j)           \
    fS[j] = *(const float4*)(gA + j * 4 * HE + (t1) * BK); }

#define A_WRITE(pbuf) { _Pragma("unroll") for (int j = 0; j < 8; ++j) {          \
    int d0_, d1_;                                                                \
    asm("v_cvt_pk_bf16_f32 %0, %1, %2" : "=v"(d0_) : "v"(fS[j].x), "v"(fS[j].y));\
    asm("v_cvt_pk_bf16_f32 %0, %1, %2" : "=v"(d1_) : "v"(fS[j].z), "v"(fS[j].w));\
    int2 w_; w_.x = d0_; w_.y = d1_;                                             \
    const int rl_ = wv * 32 + j * 4 + lh;                                        \
    *(int2*)(&Ab[pbuf][0] + rl_ * 128 + (((l15 >> 1) ^ (rl_ & 7)) << 4)          \
             + (l15 & 1) * 8) = w_; } }

#define B_ISSUE(pbuf, t1) { _Pragma("unroll") for (int j = 0; j < 4; ++j)        \
    gload_lds16(WpB + ((((long)(t1)) * 32 + wv * 4 + j) << 10) + (lane << 4),    \
                &Bb[pbuf][0] + ((wv * 4 + j) << 10)); }

#define PHASE(pb, rh, ch, STAGE_STMT) {                                          \
    const char* Ap_ = &Ab[pb][0];                                                \
    const char* Bp_ = &Bb[pb][0];                                                \
    s16x8 av_[2][4], bv_[2][2];                                                  \
    _Pragma("unroll")                                                            \
    for (int s = 0; s < 2; ++s) {                                                \
        const int ao_ = ((s * 4 + lh) ^ axr) << 4;                               \
        _Pragma("unroll")                                                        \
        for (int fr = 0; fr < 4; ++fr)                                           \
            av_[s][fr] = *(const s16x8*)(Ap_ + abase[(rh) * 4 + fr] + ao_);      \
        _Pragma("unroll")                                                        \
        for (int fc = 0; fc < 2; ++fc)                                           \
            bv_[s][fc] = *(const s16x8*)(Bp_ +                                   \
                ((s * 16 + nq * 4 + (ch) * 2 + fc) << 10) + (lane << 4));        \
    }                                                                            \
    STAGE_STMT;                                                                  \
    __builtin_amdgcn_s_setprio(1);                                               \
    _Pragma("unroll")                                                            \
    for (int s = 0; s < 2; ++s)                                                  \
        _Pragma("unroll")                                                        \
        for (int fr = 0; fr < 4; ++fr)                                           \
            _Pragma("unroll")                                                    \
            for (int fc = 0; fc < 2; ++fc)                                       \
                acc[(rh) * 4 + fr][(ch) * 2 + fc] =                              \
                    __builtin_amdgcn_mfma_f32_16x16x32_bf16(                     \
                        av_[s][fr], bv_[s][fc],                                  \
                        acc[(rh) * 4 + fr][(ch) * 2 + fc], 0, 0, 0);             \
    __builtin_amdgcn_s_setprio(0);                                               \
    __builtin_amdgcn_s_barrier();                                                \
}

    // prologue: stage tile 0 completely, drain
    A_ISSUE_H1(0); A_ISSUE_H2(0);
    B_ISSUE(0, 0);
    A_WRITE(0);                      // dataflow-waits the fS loads
    asm volatile("s_waitcnt vmcnt(0)" ::: "memory");
    asm volatile("s_waitcnt lgkmcnt(0)" ::: "memory");
    __builtin_amdgcn_s_barrier();

    for (int t = 0; t < NT; ++t) {
        const int pb = t & 1;
        if (t + 1 < NT) {
            PHASE(pb, 0, 0, A_ISSUE_H1(t + 1));
            PHASE(pb, 0, 1, A_ISSUE_H2(t + 1));
            PHASE(pb, 1, 0, B_ISSUE(pb ^ 1, t + 1));
            PHASE(pb, 1, 1, ((void)0));
            A_WRITE(pb ^ 1);         // waits A-floats only (vmcnt(4): B newer)
        } else {
            PHASE(pb, 0, 0, ((void)0));
            PHASE(pb, 0, 1, ((void)0));
            PHASE(pb, 1, 0, ((void)0));
            PHASE(pb, 1, 1, ((void)0));
        }
        asm volatile("s_waitcnt vmcnt(0)" ::: "memory");    // B gloads, ~1.5-phase slack
        asm volatile("s_waitcnt lgkmcnt(0)" ::: "memory");
        __builtin_amdgcn_s_barrier();
    }

#undef A_ISSUE_H1
#undef A_ISSUE_H2
#undef A_WRITE
#undef B_ISSUE
#undef PHASE

    // fused epilogue: partial score over this block's 256 cols
    float cv[4], vv[4];
    #pragma unroll
    for (int cfi = 0; cfi < 4; ++cfi) {
        int col = nsl * 256 + nq * 64 + (cfi >> 1) * 32 + (cfi & 1) * 16 + l15;
        cv[cfi] = C[bb * HE + col];
        vv[cfi] = VW[col];
    }
    #pragma unroll
    for (int rfi = 0; rfi < 8; ++rfi) {
        #pragma unroll
        for (int reg = 0; reg < 4; ++reg) {
            float pS = 0.f;
            #pragma unroll
            for (int cfi = 0; cfi < 4; ++cfi)
                pS += tanh_fast(acc[rfi][cfi][reg] + cv[cfi]) * vv[cfi];
            pS += __shfl_xor(pS, 1);
            pS += __shfl_xor(pS, 2);
            pS += __shfl_xor(pS, 4);
            pS += __shfl_xor(pS, 8);
            if (l15 == 0) {
                int row = mh * 128 + (rfi >> 2) * 64 + (rfi & 3) * 16 + lh * 4 + reg;
                smred[row][nq] = pS;
            }
        }
    }
    __syncthreads();
    if (tid < BM) {
        float s = smred[tid][0] + smred[tid][1] + smred[tid][2] + smred[tid][3];
        spart[(long)nsl * MTOT + m0 + tid] = s;
    }
}

// ---- softmax over S=4096 per batch row (sums 4 col-slice partials)
__global__ void k_softmax(const float* __restrict__ spart, float* __restrict__ out) {
    __shared__ float red[16];
    __shared__ float red2[16];
    int b = blockIdx.x, tid = threadIdx.x;
    float v[4];
    float mx = -1e30f;
    #pragma unroll
    for (int j = 0; j < 4; ++j) {
        long i = (long)b * SEQ + tid + j * 1024;
        v[j] = spart[i] + spart[MTOT + i] + spart[2L * MTOT + i] + spart[3L * MTOT + i];
        mx = fmaxf(mx, v[j]);
    }
    #pragma unroll
    for (int off = 32; off; off >>= 1) mx = fmaxf(mx, __shfl_xor(mx, off));
    if ((tid & 63) == 0) red[tid >> 6] = mx;
    __syncthreads();
    mx = red[0];
    #pragma unroll
    for (int i = 1; i < 16; ++i) mx = fmaxf(mx, red[i]);
    float sum = 0.f;
    #pragma unroll
    for (int j = 0; j < 4; ++j) { v[j] = expf(v[j] - mx); sum += v[j]; }
    #pragma unroll
    for (int off = 32; off; off >>= 1) sum += __shfl_xor(sum, off);
    if ((tid & 63) == 0) red2[tid >> 6] = sum;
    __syncthreads();
    sum = 0.f;
    #pragma unroll
    for (int i = 0; i < 16; ++i) sum += red2[i];
    float inv = 1.0f / sum;
    #pragma unroll
    for (int j = 0; j < 4; ++j) out[b * SEQ + tid + j * 1024] = v[j] * inv;
}

extern "C" void kernel_launch(void* const* d_in, const int* in_sizes, int n_in,
                              void* d_out, int out_size, void* d_ws, size_t ws_size,
                              hipStream_t stream)
{
    const float* hidden = (const float*)d_in[0];
    const float* enc    = (const float*)d_in[1];
    const float* W      = (const float*)d_in[2];
    const float* b_attn = (const float*)d_in[3];
    const float* v_w    = (const float*)d_in[4];
    float* out          = (float*)d_out;

    char* ws = (char*)d_ws;
    unsigned short* Wp = (unsigned short*)(ws);                        // 2 MB packed bf16 W_e
    float* cpart       = (float*)(ws + (2u << 20));                    // 1 MB
    float* Cc          = (float*)(ws + (3u << 20));                    // 128 KB
    float* spart       = (float*)(ws + (3u << 20) + (128u << 10));     // 4 x 512 KB partials

    k_pack   <<<512, 256,  0, stream>>>(W, Wp);
    k_hproj  <<<256, 1024, 0, stream>>>(hidden, W, cpart);
    k_cfinal <<<32,  1024, 0, stream>>>(cpart, b_attn, Cc);
    k_main   <<<2048, 512, 0, stream>>>(enc, Wp, Cc, v_w, spart);
    k_softmax<<<32,  1024, 0, stream>>>(spart, out);
}